// Round 9
// baseline (5124.198 us; speedup 1.0000x reference)
//
#include <hip/hip_runtime.h>

// 2-layer LSTM (H=256, T=256, B=512, I=2) + linear head.
// 256 blocks x 512 threads (2 waves/SIMD), 2 batches/block, t-loop in-kernel.
// R27: AGPR parking. R25 (fewer CUs) and R26 (depth 16) both null -> the
// per-CU stream rate is pinned ~50-53 B/cyc; only BYTES/step is a lever.
// All prior parks used asm("+v") -> crowded the 256-entry v-class (bufs +
// base live there too; every park expansion spilled). gfx950 has a
// separate 256-entry a-class (AGPR) in the unified file, and v_mfma takes
// the A-operand directly from AGPRs. Park the ENTIRE Whh2: kt0..5 in AGPR
// (48 frags = 192 a-regs, pinned via asm("+a")), kt6..7 in LDS (16 frags,
// 128 KB). Pass 2b now streams NOTHING; stream = gates1(64) + 2a(64) =
// 128 frags/wave/step (1152 -> 1024 KB/CU, -11%). NSF=128 = 0 mod 16 ->
// clean 16-buffer rotation (v-class: 64 bufs + ~70 base = ~140, safe);
// 2a's tail refills all 16 bufs with next-step gates1 frags -> 16 KB/wave
// in flight across 2b/U2/B2/U1/B1.
// Prediction: PRIMARY WRITE ~2.5MB FETCH ~7MB (else "+a" failed ->
// fallback NAPF 32); dur ~2350-2600 (1024 KB @ ~53-60 B/cyc + serial);
// Mfma 28-32%, VALU 18-22%, Occ ~24%, absmax 1.22e-4.
// A-frag (HW-verified R22-R26): lane holds row rt*16+(l&15),
// k=kt*32+(l>>4)*8..+7. B-frag: h[lane&1][kt*32+(l>>4)*8..+7] (cols 2..15
// garbage, discarded). C: col=l&15, row=(l>>4)*4+reg; lanes col<2 store.
// Kept: single stream in consumption order, rolled gates1/2a (one acc
// live per scope - R19/R26 lesson), 2 lgkm-only barriers, h fp16
// single-buffered LDS, c in regs, y deferred 1 step, bias/x in U-stages.
// No cross-block exchange. Spill detector: FETCH_SIZE/WRITE_SIZE.

typedef float vf2 __attribute__((ext_vector_type(2)));
typedef float v4f __attribute__((ext_vector_type(4)));
typedef _Float16 vh4 __attribute__((ext_vector_type(4)));
typedef _Float16 vh8 __attribute__((ext_vector_type(8)));

#define NT 512
#define TSTEPS 256
#define NSF 128           // streamed frags per wave per step (1KB each)
#define NAPF 48           // AGPR-parked frags per wave (Whh2 ktiles 0..5)
#define NLPF 16           // LDS-parked frags per wave  (Whh2 ktiles 6..7)
#define FRB 1024          // bytes per frag (64 lanes x 16B)
#define ABASE (1024 * FRB)                // 8 waves x 128 stream frags
#define LPBASE (1408 * FRB)               // 1024 + 8x48
#define FS 393216         // fp32 table offset (floats) = 1536KB/4

__global__ void prep_kernel(const float* __restrict__ W_ih1,
                            const float* __restrict__ W_hh1,
                            const float* __restrict__ b_ih1,
                            const float* __restrict__ b_hh1,
                            const float* __restrict__ W_ih2,
                            const float* __restrict__ W_hh2,
                            const float* __restrict__ b_ih2,
                            const float* __restrict__ b_hh2,
                            void* __restrict__ ws) {
    const int stride = gridDim.x * blockDim.x;
    const int idx = blockIdx.x * blockDim.x + threadIdx.x;
    _Float16* wh = (_Float16*)ws;
    float* wf = (float*)ws;
    // A-fragment layout (HW-verified): frag = 1KB; halfword index within
    // frag = lane*8 + j; element = M[w*128 + rt*16 + (lane&15)]
    //                               [kt*32 + (lane>>4)*8 + j].
    // Frag index kb = e>>9:
    //   kb<1024: stream (consumption order), w=kb>>7, f=kb&127:
    //     f<64 -> Whh1 rt=f>>3 kt=f&7 | f>=64 -> Wih2 rt=(f-64)>>3 kt=f&7
    //   kb<1408: AGPR park, p2=kb-1024: w=p2/48, p=p2%48:
    //            Whh2 rt=p/6, kt=p%6
    //   else:    LDS park, k3=kb-1408: w=k3>>4, q=k3&15:
    //            Whh2 rt=q>>1, kt=6+(q&1)
    for (int e = idx; e < 786432; e += stride) {
        int kb = e >> 9;
        int lane = (e & 511) >> 3, jj = e & 7;
        int w, rt, kt, m;
        if (kb < 1024) {
            w = kb >> 7; int f = kb & 127;
            if (f < 64) { m = 0; rt = f >> 3;        kt = f & 7; }
            else        { m = 1; rt = (f - 64) >> 3; kt = f & 7; }
        } else if (kb < 1408) {
            int p2 = kb - 1024; w = p2 / 48; int p = p2 % 48;
            m = 2; rt = p / 6; kt = p % 6;
        } else {
            int k3 = kb - 1408; w = k3 >> 4; int q = k3 & 15;
            m = 2; rt = q >> 1; kt = 6 + (q & 1);
        }
        int row = w * 128 + rt * 16 + (lane & 15);
        int k   = kt * 32 + ((lane >> 4) << 3) + jj;
        float v = (m == 0) ? W_hh1[row * 256 + k]
                : (m == 1) ? W_ih2[row * 256 + k]
                           : W_hh2[row * 256 + k];
        wh[e] = (_Float16)v;
    }
    for (int j = idx; j < 1024; j += stride) {
        wf[FS + j]        = W_ih1[j * 2 + 0];
        wf[FS + 1024 + j] = W_ih1[j * 2 + 1];
        wf[FS + 2048 + j] = b_ih1[j] + b_hh1[j];
        wf[FS + 3072 + j] = b_ih2[j] + b_hh2[j];
    }
}

__device__ __forceinline__ float sig_(float v) {
    return 1.f / (1.f + __expf(-v));
}
__device__ __forceinline__ float tanh_(float v) {
    return 1.f - 2.f / (__expf(2.f * v) + 1.f);
}
__device__ __forceinline__ v4f mfma16(vh8 a, vh8 b, v4f c) {
    return __builtin_amdgcn_mfma_f32_16x16x32_f16(a, b, c, 0, 0, 0);
}

// lgkm-only barrier: LDS drained, weight-stream vmem stays in flight.
#define BARRIER() __asm__ volatile("s_waitcnt lgkmcnt(0)\ns_barrier" ::: "memory")

__global__ __launch_bounds__(NT, 2) void lstm_kernel(
    const float* __restrict__ x,      // (512, 256, 2)
    const void* __restrict__ ws,
    const float* __restrict__ W_lin,  // (2, 256)
    const float* __restrict__ b_lin,  // (2,)
    float* __restrict__ out)          // (512, 256, 2)
{
    __shared__ float g1buf[2][1024];               // raw Whh1*h1 [batch][row]
    __shared__ float g2buf[2][1024];               // gates2 gemm (partial/final)
    __shared__ __align__(16) _Float16 h1s[2][256]; // h1 [batch][unit]
    __shared__ __align__(16) _Float16 h2s[2][256]; // h2
    __shared__ __align__(16) char lds_park[NLPF * 8 * FRB]; // 128 KB

    const int tid = threadIdx.x;
    const int lane = tid & 63, w = tid >> 6;       // wave id = rowgroup
    const int u = tid & 255, bu = tid >> 8;        // cell-update: unit, batch
    const int b0 = blockIdx.x * 2;
    const char* wstream = (const char*)ws;
    const float* wf = (const float*)ws;
    const int l16 = lane * 16;

    // U-stage affine constants: rows u, 256+u, 512+u, 768+u
    float wxa[4], wxb[4], b1c[4], b2c[4];
    #pragma unroll
    for (int g = 0; g < 4; ++g) {
        int r = g * 256 + u;
        wxa[g] = wf[FS + r];        wxb[g] = wf[FS + 1024 + r];
        b1c[g] = wf[FS + 2048 + r]; b2c[g] = wf[FS + 3072 + r];
    }

    // y-head: waves 0..3 -> (batch ob, output oo); lane covers 4 units
    const int ob = (w >> 1) & 1, oo = w & 1;
    const float wl0 = W_lin[oo * 256 + 4 * lane + 0];
    const float wl1 = W_lin[oo * 256 + 4 * lane + 1];
    const float wl2 = W_lin[oo * 256 + 4 * lane + 2];
    const float wl3 = W_lin[oo * 256 + 4 * lane + 3];
    const float blin = b_lin[oo];

    // zero initial h and g1buf (t=0: Whh1*h1(-1) = 0)
    ((_Float16*)h1s)[tid] = (_Float16)0.f;
    ((_Float16*)h2s)[tid] = (_Float16)0.f;
    g1buf[0][tid] = 0.f; g1buf[0][512 + tid] = 0.f;
    g1buf[1][tid] = 0.f; g1buf[1][512 + tid] = 0.f;

    float c1 = 0.f, c2 = 0.f;

    // stage LDS parks (kt6,7): lds[((q*8+w)<<10)+l16]
    for (int q = 0; q < NLPF; ++q) {
        *(vh8*)&lds_park[(((q << 3) + w) << 10) + l16] =
            *(const vh8*)(wstream + LPBASE + (((w << 4) + q) << 10) + l16);
    }

    // AGPR parks: 48 frags (Whh2 kt0..5 x 8 rowtiles), PINNED to a-class.
    // v_mfma reads the A-operand directly from AGPRs; v-class stays free
    // for the 16 stream buffers + base.
    vh8 wrega[NAPF];
    #pragma unroll
    for (int p = 0; p < NAPF; ++p) {
        union { vh8 v; float f[4]; } tpk;
        tpk.v = *(const vh8*)(wstream + ABASE + ((w * NAPF + p) << 10) + l16);
        asm volatile("" : "+a"(tpk.f[0]), "+a"(tpk.f[1]),
                          "+a"(tpk.f[2]), "+a"(tpk.f[3]));
        wrega[p] = tpk.v;
    }

    // single stream: per-wave base, 16 named rotating buffers, uniform sp.
    // Invariant: consumption c (0..127 per step) uses slot c&15 == frag c.
    const char* wbase = wstream + (size_t)w * (NSF * FRB);
    int sp = 0;
    vh8 B0, B1, B2, B3, B4, B5, B6, B7, B8, B9, B10, B11, B12, B13, B14, B15;
    auto LDA = [&](vh8& d) {
        d = *(const vh8*)(wbase + sp + l16);
        sp += FRB; if (sp == NSF * FRB) sp = 0;
    };
    LDA(B0); LDA(B1); LDA(B2);  LDA(B3);  LDA(B4);  LDA(B5);  LDA(B6);  LDA(B7);
    LDA(B8); LDA(B9); LDA(B10); LDA(B11); LDA(B12); LDA(B13); LDA(B14); LDA(B15);

    // B-fragment from h LDS: col=lane&15 (only 0/1 real; garbage cols read
    // batch lane&1 - finite, discarded). k = kt*32 + (lane>>4)*8 .. +7.
    auto bfrag = [&](const _Float16 (*hp)[256], int kt) -> vh8 {
        return *(const vh8*)&hp[lane & 1][kt * 32 + ((lane >> 4) << 3)];
    };

    const int bx = b0 + bu;
    vf2 xv = *(const vf2*)(x + (size_t)bx * 512);   // x(0)

    __syncthreads();   // init barrier (full drain once is fine)

    #pragma unroll 1
    for (int t = 0; t < TSTEPS; ++t) {
        // ---- U1: gates1(t) = g1buf(raw) + b1 + Wih1*x(t) -> h1(t) ----
        {
            float p0 = g1buf[bu][u]       + b1c[0] + wxa[0] * xv.x + wxb[0] * xv.y;
            float p1 = g1buf[bu][256 + u] + b1c[1] + wxa[1] * xv.x + wxb[1] * xv.y;
            float p2 = g1buf[bu][512 + u] + b1c[2] + wxa[2] * xv.x + wxb[2] * xv.y;
            float p3 = g1buf[bu][768 + u] + b1c[3] + wxa[3] * xv.x + wxb[3] * xv.y;
            c1 = sig_(p1) * c1 + sig_(p0) * tanh_(p2);
            h1s[bu][u] = (_Float16)(sig_(p3) * tanh_(c1));
        }
        {   // prefetch x(t+1) (wraps harmlessly)
            const int tn = (t + 1) & (TSTEPS - 1);
            xv = *(const vf2*)(x + (size_t)bx * 512 + tn * 2);
        }
        BARRIER();   // B1: h1(t) visible; h2(t-1) (from prev U2) visible

        // ---- y(t-1) (deferred; h2(t-1) stable in this epoch) ----
        if (t > 0 && w < 4) {
            vh4 hv = *(const vh4*)&h2s[ob][4 * lane];
            float s = (float)hv.x * wl0 + (float)hv.y * wl1
                    + (float)hv.z * wl2 + (float)hv.w * wl3;
            #pragma unroll
            for (int m = 32; m >= 1; m >>= 1) s += __shfl_xor(s, m, 64);
            if (lane == 0)
                out[(size_t)(b0 + ob) * 512 + (t - 1) * 2 + oo] = s + blin;
        }

        // ---- gates1(t+1) raw = Whh1 * h1(t)  [consumptions 0..63;
        //      2 rowtiles per rolled iter, one acc live per scope] ----
        #pragma unroll 1
        for (int rp = 0; rp < 4; ++rp) {
            {
                v4f a0 = {0.f, 0.f, 0.f, 0.f};
                a0 = mfma16(B0, bfrag(h1s, 0), a0); LDA(B0);
                a0 = mfma16(B1, bfrag(h1s, 1), a0); LDA(B1);
                a0 = mfma16(B2, bfrag(h1s, 2), a0); LDA(B2);
                a0 = mfma16(B3, bfrag(h1s, 3), a0); LDA(B3);
                a0 = mfma16(B4, bfrag(h1s, 4), a0); LDA(B4);
                a0 = mfma16(B5, bfrag(h1s, 5), a0); LDA(B5);
                a0 = mfma16(B6, bfrag(h1s, 6), a0); LDA(B6);
                a0 = mfma16(B7, bfrag(h1s, 7), a0); LDA(B7);
                if ((lane & 15) < 2)
                    *(v4f*)&g1buf[lane & 15][w * 128 + (2 * rp) * 16 + ((lane >> 4) << 2)] = a0;
            }
            {
                v4f a1 = {0.f, 0.f, 0.f, 0.f};
                a1 = mfma16(B8,  bfrag(h1s, 0), a1); LDA(B8);
                a1 = mfma16(B9,  bfrag(h1s, 1), a1); LDA(B9);
                a1 = mfma16(B10, bfrag(h1s, 2), a1); LDA(B10);
                a1 = mfma16(B11, bfrag(h1s, 3), a1); LDA(B11);
                a1 = mfma16(B12, bfrag(h1s, 4), a1); LDA(B12);
                a1 = mfma16(B13, bfrag(h1s, 5), a1); LDA(B13);
                a1 = mfma16(B14, bfrag(h1s, 6), a1); LDA(B14);
                a1 = mfma16(B15, bfrag(h1s, 7), a1); LDA(B15);
                if ((lane & 15) < 2)
                    *(v4f*)&g1buf[lane & 15][w * 128 + (2 * rp + 1) * 16 + ((lane >> 4) << 2)] = a1;
            }
        }

        // ---- gates2 pass 2a: partial = Wih2 * h1(t)  [cons. 64..127] ----
        // Tail iterations refill all 16 bufs with NEXT step's gates1 frags
        // (sp wraps at 128): 16 KB/wave in flight across 2b/U2/B2/U1/B1.
        #pragma unroll 1
        for (int rp = 0; rp < 4; ++rp) {
            {
                v4f a0 = {0.f, 0.f, 0.f, 0.f};
                a0 = mfma16(B0, bfrag(h1s, 0), a0); LDA(B0);
                a0 = mfma16(B1, bfrag(h1s, 1), a0); LDA(B1);
                a0 = mfma16(B2, bfrag(h1s, 2), a0); LDA(B2);
                a0 = mfma16(B3, bfrag(h1s, 3), a0); LDA(B3);
                a0 = mfma16(B4, bfrag(h1s, 4), a0); LDA(B4);
                a0 = mfma16(B5, bfrag(h1s, 5), a0); LDA(B5);
                a0 = mfma16(B6, bfrag(h1s, 6), a0); LDA(B6);
                a0 = mfma16(B7, bfrag(h1s, 7), a0); LDA(B7);
                if ((lane & 15) < 2)
                    *(v4f*)&g2buf[lane & 15][w * 128 + (2 * rp) * 16 + ((lane >> 4) << 2)] = a0;
            }
            {
                v4f a1 = {0.f, 0.f, 0.f, 0.f};
                a1 = mfma16(B8,  bfrag(h1s, 0), a1); LDA(B8);
                a1 = mfma16(B9,  bfrag(h1s, 1), a1); LDA(B9);
                a1 = mfma16(B10, bfrag(h1s, 2), a1); LDA(B10);
                a1 = mfma16(B11, bfrag(h1s, 3), a1); LDA(B11);
                a1 = mfma16(B12, bfrag(h1s, 4), a1); LDA(B12);
                a1 = mfma16(B13, bfrag(h1s, 5), a1); LDA(B13);
                a1 = mfma16(B14, bfrag(h1s, 6), a1); LDA(B14);
                a1 = mfma16(B15, bfrag(h1s, 7), a1); LDA(B15);
                if ((lane & 15) < 2)
                    *(v4f*)&g2buf[lane & 15][w * 128 + (2 * rp + 1) * 16 + ((lane >> 4) << 2)] = a1;
            }
        }

        // ---- gates2 pass 2b: += Whh2 * h2(t-1)  [NO stream traffic:
        //      kt0..5 AGPR parks (static idx), kt6..7 LDS parks] ----
#define P2B(RT)                                                                \
        {                                                                      \
            v4f acc = {0.f, 0.f, 0.f, 0.f};                                    \
            if ((lane & 15) < 2)                                               \
                acc = *(const v4f*)&g2buf[lane & 15]                           \
                        [w * 128 + RT * 16 + ((lane >> 4) << 2)];              \
            acc = mfma16(wrega[RT * 6 + 0], bfrag(h2s, 0), acc);               \
            acc = mfma16(wrega[RT * 6 + 1], bfrag(h2s, 1), acc);               \
            acc = mfma16(wrega[RT * 6 + 2], bfrag(h2s, 2), acc);               \
            acc = mfma16(wrega[RT * 6 + 3], bfrag(h2s, 3), acc);               \
            acc = mfma16(wrega[RT * 6 + 4], bfrag(h2s, 4), acc);               \
            acc = mfma16(wrega[RT * 6 + 5], bfrag(h2s, 5), acc);               \
            {                                                                  \
                vh8 A6 = *(const vh8*)                                         \
                    &lds_park[((((RT * 2 + 0) << 3) + w) << 10) + l16];        \
                acc = mfma16(A6, bfrag(h2s, 6), acc);                          \
            }                                                                  \
            {                                                                  \
                vh8 A7 = *(const vh8*)                                         \
                    &lds_park[((((RT * 2 + 1) << 3) + w) << 10) + l16];        \
                acc = mfma16(A7, bfrag(h2s, 7), acc);                          \
            }                                                                  \
            if ((lane & 15) < 2)                                               \
                *(v4f*)&g2buf[lane & 15]                                       \
                    [w * 128 + RT * 16 + ((lane >> 4) << 2)] = acc;            \
        }
        P2B(0) P2B(1) P2B(2) P2B(3) P2B(4) P2B(5) P2B(6) P2B(7)
#undef P2B
        BARRIER();   // B2: g1buf/g2buf visible

        // ---- U2: gates2 + b2 -> h2(t) ----
        {
            float q0 = g2buf[bu][u]       + b2c[0];
            float q1 = g2buf[bu][256 + u] + b2c[1];
            float q2 = g2buf[bu][512 + u] + b2c[2];
            float q3 = g2buf[bu][768 + u] + b2c[3];
            c2 = sig_(q1) * c2 + sig_(q0) * tanh_(q2);
            h2s[bu][u] = (_Float16)(sig_(q3) * tanh_(c2));
        }
        // no barrier: next iteration's B1 publishes h2(t) before it's read
    }

    // ---- tail: y(255) ----
    BARRIER();
    if (w < 4) {
        vh4 hv = *(const vh4*)&h2s[ob][4 * lane];
        float s = (float)hv.x * wl0 + (float)hv.y * wl1
                + (float)hv.z * wl2 + (float)hv.w * wl3;
        #pragma unroll
        for (int m = 32; m >= 1; m >>= 1) s += __shfl_xor(s, m, 64);
        if (lane == 0)
            out[(size_t)(b0 + ob) * 512 + 255 * 2 + oo] = s + blin;
    }
}

extern "C" void kernel_launch(void* const* d_in, const int* in_sizes, int n_in,
                              void* d_out, int out_size, void* d_ws, size_t ws_size,
                              hipStream_t stream) {
    const float* x     = (const float*)d_in[0];
    const float* W_ih1 = (const float*)d_in[1];
    const float* W_hh1 = (const float*)d_in[2];
    const float* b_ih1 = (const float*)d_in[3];
    const float* b_hh1 = (const float*)d_in[4];
    const float* W_ih2 = (const float*)d_in[5];
    const float* W_hh2 = (const float*)d_in[6];
    const float* b_ih2 = (const float*)d_in[7];
    const float* b_hh2 = (const float*)d_in[8];
    const float* W_lin = (const float*)d_in[9];
    const float* b_lin = (const float*)d_in[10];
    float* out = (float*)d_out;

    prep_kernel<<<256, 256, 0, stream>>>(W_ih1, W_hh1, b_ih1, b_hh1,
                                         W_ih2, W_hh2, b_ih2, b_hh2, d_ws);
    lstm_kernel<<<256, NT, 0, stream>>>(x, d_ws, W_lin, b_lin, out);
}

// Round 10
// 2748.323 us; speedup vs baseline: 1.8645x; 1.8645x over previous
//
#include <hip/hip_runtime.h>

// 2-layer LSTM (H=256, T=256, B=512, I=2) + linear head.
// 256 blocks x 512 threads (2 waves/SIMD), 2 batches/block, t-loop in-kernel.
// R28: hoist B-fragments. R27 post-mortem: gfx950 VGPR/AGPR file is
// UNIFIED (docs explicit) - "+a" parking gave no capacity, 326 regs
// spilled (FETCH 7.2GB). Park capacity is capped at R24's level.
// New target: the 3.4us/step non-byte intercept (fit R24/R26). Evidence:
// SQ_LDS_BANK_CONFLICT 1.007e8 == blocks x steps x waves x 192 = one
// 2-way-conflicted ds_read_b128 per MFMA - h re-read per rowtile though
// invariant per phase; 384 reads/SIMD/step on the lgkm pipe serialized
// into MFMA waits. Fix: hoist 8 h-frags to named regs once per phase
// (h1 for gates1+2a; same 32 regs reused for h2 in 2b) -> 192 -> 24
// reads/wave/step. Paid by NVPF 32->24 (kt4 joins stream: NSF 144->152,
// +64KB/step ~ +0.4us marginal).
// Prediction: BANK_CONFLICT -> ~2.1e7 (mechanism check); dur ~2450-2650
// if LDS chain was exposed; >=2705 + clean FETCH/WRITE -> null, R24 is
// the structural ceiling (roofline). FETCH ~7.5MB WRITE ~2.5MB (spill
// detector; fallback: drop hoist). Mfma 26-31%, VALU 18-22%.
// A-frag (HW-verified R22-R27): lane holds row rt*16+(l&15),
// k=kt*32+(l>>4)*8..+7. B-frag: h[lane&1][kt*32+(l>>4)*8..+7] (cols 2..15
// garbage, discarded). C: col=l&15, row=(l>>4)*4+reg; lanes col<2 store.
// Kept from R24 (best, 2705): single stream in consumption order, 8 named
// rotating bufs (depth 16 null - R26), rolled gates1/2a (R7-R10/R22: big
// unrolled schedules spill), 24 VGPR parks pinned "+v" (static idx),
// 16 LDS park frags (kt6,7; 128KB), 2 lgkm-only barriers, h fp16
// single-buffered LDS, c in regs, y deferred 1 step, bias/x in U-stages.
// No cross-block exchange. Spill detector: FETCH_SIZE/WRITE_SIZE.

typedef float vf2 __attribute__((ext_vector_type(2)));
typedef float v4f __attribute__((ext_vector_type(4)));
typedef _Float16 vh4 __attribute__((ext_vector_type(4)));
typedef _Float16 vh8 __attribute__((ext_vector_type(8)));

#define NT 512
#define TSTEPS 256
#define NSF 152           // streamed frags per wave per step (1KB each)
#define NVPF 24           // VGPR-parked frags per wave (Whh2 ktiles 1..3)
#define NLPF 16           // LDS-parked frags per wave  (Whh2 ktiles 6..7)
#define FRB 1024          // bytes per frag (64 lanes x 16B)
#define VPBASE (1216 * FRB)               // 8 waves x 152 stream frags
#define LPBASE (1408 * FRB)               // 1216 + 8x24
#define FS 393216         // fp32 table offset (floats) = 1536KB/4

__global__ void prep_kernel(const float* __restrict__ W_ih1,
                            const float* __restrict__ W_hh1,
                            const float* __restrict__ b_ih1,
                            const float* __restrict__ b_hh1,
                            const float* __restrict__ W_ih2,
                            const float* __restrict__ W_hh2,
                            const float* __restrict__ b_ih2,
                            const float* __restrict__ b_hh2,
                            void* __restrict__ ws) {
    const int stride = gridDim.x * blockDim.x;
    const int idx = blockIdx.x * blockDim.x + threadIdx.x;
    _Float16* wh = (_Float16*)ws;
    float* wf = (float*)ws;
    // A-fragment layout (HW-verified): frag = 1KB; halfword index within
    // frag = lane*8 + j; element = M[w*128 + rt*16 + (lane&15)]
    //                               [kt*32 + (lane>>4)*8 + j].
    // Frag index kb = e>>9 (stream region in CONSUMPTION order):
    //   kb<1216: stream, w=kb/152, f=kb%152:
    //     f<64  -> Whh1 rt=f>>3, kt=f&7
    //     f<128 -> Wih2 rt=(f-64)>>3, kt=f&7
    //     else  -> q=f-128: Whh2 rt=q/3, pos=q%3, kt={0,4,5}[pos]
    //   kb<1408: VGPR park, p2=kb-1216: w=p2/24, p=p2%24:
    //            Whh2 rt=p/3, kt=1+p%3
    //   else:    LDS park, k3=kb-1408: w=k3>>4, q=k3&15:
    //            Whh2 rt=q>>1, kt=6+(q&1)
    for (int e = idx; e < 786432; e += stride) {
        int kb = e >> 9;
        int lane = (e & 511) >> 3, jj = e & 7;
        int w, rt, kt, m;
        if (kb < 1216) {
            w = kb / 152; int f = kb % 152;
            if (f < 64)       { m = 0; rt = f >> 3;        kt = f & 7; }
            else if (f < 128) { m = 1; rt = (f - 64) >> 3; kt = f & 7; }
            else {
                int q = f - 128; m = 2; rt = q / 3; int pos = q % 3;
                kt = (pos == 0) ? 0 : (pos == 1) ? 4 : 5;
            }
        } else if (kb < 1408) {
            int p2 = kb - 1216; w = p2 / 24; int p = p2 % 24;
            m = 2; rt = p / 3; kt = 1 + p % 3;
        } else {
            int k3 = kb - 1408; w = k3 >> 4; int q = k3 & 15;
            m = 2; rt = q >> 1; kt = 6 + (q & 1);
        }
        int row = w * 128 + rt * 16 + (lane & 15);
        int k   = kt * 32 + ((lane >> 4) << 3) + jj;
        float v = (m == 0) ? W_hh1[row * 256 + k]
                : (m == 1) ? W_ih2[row * 256 + k]
                           : W_hh2[row * 256 + k];
        wh[e] = (_Float16)v;
    }
    for (int j = idx; j < 1024; j += stride) {
        wf[FS + j]        = W_ih1[j * 2 + 0];
        wf[FS + 1024 + j] = W_ih1[j * 2 + 1];
        wf[FS + 2048 + j] = b_ih1[j] + b_hh1[j];
        wf[FS + 3072 + j] = b_ih2[j] + b_hh2[j];
    }
}

__device__ __forceinline__ float sig_(float v) {
    return 1.f / (1.f + __expf(-v));
}
__device__ __forceinline__ float tanh_(float v) {
    return 1.f - 2.f / (__expf(2.f * v) + 1.f);
}
__device__ __forceinline__ v4f mfma16(vh8 a, vh8 b, v4f c) {
    return __builtin_amdgcn_mfma_f32_16x16x32_f16(a, b, c, 0, 0, 0);
}

// lgkm-only barrier: LDS drained, weight-stream vmem stays in flight.
#define BARRIER() __asm__ volatile("s_waitcnt lgkmcnt(0)\ns_barrier" ::: "memory")

__global__ __launch_bounds__(NT, 2) void lstm_kernel(
    const float* __restrict__ x,      // (512, 256, 2)
    const void* __restrict__ ws,
    const float* __restrict__ W_lin,  // (2, 256)
    const float* __restrict__ b_lin,  // (2,)
    float* __restrict__ out)          // (512, 256, 2)
{
    __shared__ float g1buf[2][1024];               // raw Whh1*h1 [batch][row]
    __shared__ float g2buf[2][1024];               // gates2 gemm (partial/final)
    __shared__ __align__(16) _Float16 h1s[2][256]; // h1 [batch][unit]
    __shared__ __align__(16) _Float16 h2s[2][256]; // h2
    __shared__ __align__(16) char lds_park[NLPF * 8 * FRB]; // 128 KB

    const int tid = threadIdx.x;
    const int lane = tid & 63, w = tid >> 6;       // wave id = rowgroup
    const int u = tid & 255, bu = tid >> 8;        // cell-update: unit, batch
    const int b0 = blockIdx.x * 2;
    const char* wstream = (const char*)ws;
    const float* wf = (const float*)ws;
    const int l16 = lane * 16;

    // U-stage affine constants: rows u, 256+u, 512+u, 768+u
    float wxa[4], wxb[4], b1c[4], b2c[4];
    #pragma unroll
    for (int g = 0; g < 4; ++g) {
        int r = g * 256 + u;
        wxa[g] = wf[FS + r];        wxb[g] = wf[FS + 1024 + r];
        b1c[g] = wf[FS + 2048 + r]; b2c[g] = wf[FS + 3072 + r];
    }

    // y-head: waves 0..3 -> (batch ob, output oo); lane covers 4 units
    const int ob = (w >> 1) & 1, oo = w & 1;
    const float wl0 = W_lin[oo * 256 + 4 * lane + 0];
    const float wl1 = W_lin[oo * 256 + 4 * lane + 1];
    const float wl2 = W_lin[oo * 256 + 4 * lane + 2];
    const float wl3 = W_lin[oo * 256 + 4 * lane + 3];
    const float blin = b_lin[oo];

    // zero initial h and g1buf (t=0: Whh1*h1(-1) = 0)
    ((_Float16*)h1s)[tid] = (_Float16)0.f;
    ((_Float16*)h2s)[tid] = (_Float16)0.f;
    g1buf[0][tid] = 0.f; g1buf[0][512 + tid] = 0.f;
    g1buf[1][tid] = 0.f; g1buf[1][512 + tid] = 0.f;

    float c1 = 0.f, c2 = 0.f;

    // stage LDS parks (kt6,7): lds[((q*8+w)<<10)+l16]
    for (int q = 0; q < NLPF; ++q) {
        *(vh8*)&lds_park[(((q << 3) + w) << 10) + l16] =
            *(const vh8*)(wstream + LPBASE + (((w << 4) + q) << 10) + l16);
    }

    // VGPR parks: 24 frags (Whh2 ktiles 1..3 x 8 rowtiles), PINNED.
    vh8 wreg[NVPF];
    #pragma unroll
    for (int p = 0; p < NVPF; ++p) {
        union { vh8 v; float f[4]; } tpk;
        tpk.v = *(const vh8*)(wstream + VPBASE + ((w * NVPF + p) << 10) + l16);
        asm volatile("" : "+v"(tpk.f[0]), "+v"(tpk.f[1]),
                          "+v"(tpk.f[2]), "+v"(tpk.f[3]));
        wreg[p] = tpk.v;
    }

    // single stream: per-wave base, 8 named rotating buffers, uniform sp.
    // Invariant: consumption c (0..151 per step) uses slot c&7 == frag c.
    const char* wbase = wstream + (size_t)w * (NSF * FRB);
    int sp = 0;
    vh8 B0, B1, B2, B3, B4, B5, B6, B7;
    auto LDA = [&](vh8& d) {
        d = *(const vh8*)(wbase + sp + l16);
        sp += FRB; if (sp == NSF * FRB) sp = 0;
    };
    LDA(B0); LDA(B1); LDA(B2); LDA(B3);
    LDA(B4); LDA(B5); LDA(B6); LDA(B7);

    // B-fragment from h LDS: col=lane&15 (only 0/1 real; garbage cols read
    // batch lane&1 - finite, discarded). k = kt*32 + (lane>>4)*8 .. +7.
    auto bfrag = [&](const _Float16 (*hp)[256], int kt) -> vh8 {
        return *(const vh8*)&hp[lane & 1][kt * 32 + ((lane >> 4) << 3)];
    };

    const int bx = b0 + bu;
    vf2 xv = *(const vf2*)(x + (size_t)bx * 512);   // x(0)

    __syncthreads();   // init barrier (full drain once is fine)

    #pragma unroll 1
    for (int t = 0; t < TSTEPS; ++t) {
        // ---- U1: gates1(t) = g1buf(raw) + b1 + Wih1*x(t) -> h1(t) ----
        {
            float p0 = g1buf[bu][u]       + b1c[0] + wxa[0] * xv.x + wxb[0] * xv.y;
            float p1 = g1buf[bu][256 + u] + b1c[1] + wxa[1] * xv.x + wxb[1] * xv.y;
            float p2 = g1buf[bu][512 + u] + b1c[2] + wxa[2] * xv.x + wxb[2] * xv.y;
            float p3 = g1buf[bu][768 + u] + b1c[3] + wxa[3] * xv.x + wxb[3] * xv.y;
            c1 = sig_(p1) * c1 + sig_(p0) * tanh_(p2);
            h1s[bu][u] = (_Float16)(sig_(p3) * tanh_(c1));
        }
        {   // prefetch x(t+1) (wraps harmlessly)
            const int tn = (t + 1) & (TSTEPS - 1);
            xv = *(const vf2*)(x + (size_t)bx * 512 + tn * 2);
        }
        BARRIER();   // B1: h1(t) visible; h2(t-1) (from prev U2) visible

        // ---- y(t-1) (deferred; h2(t-1) stable in this epoch) ----
        if (t > 0 && w < 4) {
            vh4 hv = *(const vh4*)&h2s[ob][4 * lane];
            float s = (float)hv.x * wl0 + (float)hv.y * wl1
                    + (float)hv.z * wl2 + (float)hv.w * wl3;
            #pragma unroll
            for (int m = 32; m >= 1; m >>= 1) s += __shfl_xor(s, m, 64);
            if (lane == 0)
                out[(size_t)(b0 + ob) * 512 + (t - 1) * 2 + oo] = s + blin;
        }

        // ---- hoist h1 B-fragments ONCE (invariant through gates1 + 2a);
        //      replaces 128 per-rowtile ds_read_b128 with 8 ----
        vh8 hf0 = bfrag(h1s, 0), hf1 = bfrag(h1s, 1);
        vh8 hf2 = bfrag(h1s, 2), hf3 = bfrag(h1s, 3);
        vh8 hf4 = bfrag(h1s, 4), hf5 = bfrag(h1s, 5);
        vh8 hf6 = bfrag(h1s, 6), hf7 = bfrag(h1s, 7);

        // ---- gates1(t+1) raw = Whh1 * h1(t)  [consumptions 0..63] ----
        #pragma unroll 1
        for (int rt = 0; rt < 8; ++rt) {
            v4f acc = {0.f, 0.f, 0.f, 0.f};
            acc = mfma16(B0, hf0, acc); LDA(B0);
            acc = mfma16(B1, hf1, acc); LDA(B1);
            acc = mfma16(B2, hf2, acc); LDA(B2);
            acc = mfma16(B3, hf3, acc); LDA(B3);
            acc = mfma16(B4, hf4, acc); LDA(B4);
            acc = mfma16(B5, hf5, acc); LDA(B5);
            acc = mfma16(B6, hf6, acc); LDA(B6);
            acc = mfma16(B7, hf7, acc); LDA(B7);
            if ((lane & 15) < 2)
                *(v4f*)&g1buf[lane & 15][w * 128 + rt * 16 + ((lane >> 4) << 2)] = acc;
        }

        // ---- gates2 pass 2a: partial = Wih2 * h1(t)  [cons. 64..127] ----
        #pragma unroll 1
        for (int rt = 0; rt < 8; ++rt) {
            v4f acc = {0.f, 0.f, 0.f, 0.f};
            acc = mfma16(B0, hf0, acc); LDA(B0);
            acc = mfma16(B1, hf1, acc); LDA(B1);
            acc = mfma16(B2, hf2, acc); LDA(B2);
            acc = mfma16(B3, hf3, acc); LDA(B3);
            acc = mfma16(B4, hf4, acc); LDA(B4);
            acc = mfma16(B5, hf5, acc); LDA(B5);
            acc = mfma16(B6, hf6, acc); LDA(B6);
            acc = mfma16(B7, hf7, acc); LDA(B7);
            if ((lane & 15) < 2)
                *(v4f*)&g2buf[lane & 15][w * 128 + rt * 16 + ((lane >> 4) << 2)] = acc;
        }

        // ---- re-hoist for h2 (same 32 regs; h1 frags dead) ----
        hf0 = bfrag(h2s, 0); hf1 = bfrag(h2s, 1);
        hf2 = bfrag(h2s, 2); hf3 = bfrag(h2s, 3);
        hf4 = bfrag(h2s, 4); hf5 = bfrag(h2s, 5);
        hf6 = bfrag(h2s, 6); hf7 = bfrag(h2s, 7);

        // ---- gates2 pass 2b: += Whh2 * h2(t-1)  [cons. 128..151 = 8 rt x
        //      3 streamed kt {0,4,5}; kt1..3 VGPR parks (static idx);
        //      kt6..7 LDS parks]. Refills wrap into next step's frags. ----
#define P2B(RT, BA, BB, BC)                                                    \
        {                                                                      \
            v4f acc = {0.f, 0.f, 0.f, 0.f};                                    \
            if ((lane & 15) < 2)                                               \
                acc = *(const v4f*)&g2buf[lane & 15]                           \
                        [w * 128 + RT * 16 + ((lane >> 4) << 2)];              \
            acc = mfma16(BA, hf0, acc); LDA(BA);                               \
            acc = mfma16(wreg[RT * 3 + 0], hf1, acc);                          \
            acc = mfma16(wreg[RT * 3 + 1], hf2, acc);                          \
            acc = mfma16(wreg[RT * 3 + 2], hf3, acc);                          \
            acc = mfma16(BB, hf4, acc); LDA(BB);                               \
            acc = mfma16(BC, hf5, acc); LDA(BC);                               \
            {                                                                  \
                vh8 A6 = *(const vh8*)                                         \
                    &lds_park[((((RT * 2 + 0) << 3) + w) << 10) + l16];        \
                acc = mfma16(A6, hf6, acc);                                    \
            }                                                                  \
            {                                                                  \
                vh8 A7 = *(const vh8*)                                         \
                    &lds_park[((((RT * 2 + 1) << 3) + w) << 10) + l16];        \
                acc = mfma16(A7, hf7, acc);                                    \
            }                                                                  \
            if ((lane & 15) < 2)                                               \
                *(v4f*)&g2buf[lane & 15]                                       \
                    [w * 128 + RT * 16 + ((lane >> 4) << 2)] = acc;            \
        }
        // consumption slots: c = 128 + 3*RT + {0,1,2}, slot = c & 7
        P2B(0, B0, B1, B2) P2B(1, B3, B4, B5) P2B(2, B6, B7, B0)
        P2B(3, B1, B2, B3) P2B(4, B4, B5, B6) P2B(5, B7, B0, B1)
        P2B(6, B2, B3, B4) P2B(7, B5, B6, B7)
#undef P2B
        BARRIER();   // B2: g1buf/g2buf visible

        // ---- U2: gates2 + b2 -> h2(t) ----
        {
            float q0 = g2buf[bu][u]       + b2c[0];
            float q1 = g2buf[bu][256 + u] + b2c[1];
            float q2 = g2buf[bu][512 + u] + b2c[2];
            float q3 = g2buf[bu][768 + u] + b2c[3];
            c2 = sig_(q1) * c2 + sig_(q0) * tanh_(q2);
            h2s[bu][u] = (_Float16)(sig_(q3) * tanh_(c2));
        }
        // no barrier: next iteration's B1 publishes h2(t) before it's read
    }

    // ---- tail: y(255) ----
    BARRIER();
    if (w < 4) {
        vh4 hv = *(const vh4*)&h2s[ob][4 * lane];
        float s = (float)hv.x * wl0 + (float)hv.y * wl1
                + (float)hv.z * wl2 + (float)hv.w * wl3;
        #pragma unroll
        for (int m = 32; m >= 1; m >>= 1) s += __shfl_xor(s, m, 64);
        if (lane == 0)
            out[(size_t)(b0 + ob) * 512 + 255 * 2 + oo] = s + blin;
    }
}

extern "C" void kernel_launch(void* const* d_in, const int* in_sizes, int n_in,
                              void* d_out, int out_size, void* d_ws, size_t ws_size,
                              hipStream_t stream) {
    const float* x     = (const float*)d_in[0];
    const float* W_ih1 = (const float*)d_in[1];
    const float* W_hh1 = (const float*)d_in[2];
    const float* b_ih1 = (const float*)d_in[3];
    const float* b_hh1 = (const float*)d_in[4];
    const float* W_ih2 = (const float*)d_in[5];
    const float* W_hh2 = (const float*)d_in[6];
    const float* b_ih2 = (const float*)d_in[7];
    const float* b_hh2 = (const float*)d_in[8];
    const float* W_lin = (const float*)d_in[9];
    const float* b_lin = (const float*)d_in[10];
    float* out = (float*)d_out;

    prep_kernel<<<256, 256, 0, stream>>>(W_ih1, W_hh1, b_ih1, b_hh1,
                                         W_ih2, W_hh2, b_ih2, b_hh2, d_ws);
    lstm_kernel<<<256, NT, 0, stream>>>(x, d_ws, W_lin, b_lin, out);
}